// Round 5
// baseline (628.472 us; speedup 1.0000x reference)
//
#include <hip/hip_runtime.h>
#include <hip/hip_fp16.h>

// Problem constants (fixed by the reference)
#define NN 50000      // nodes
#define EE 800000     // edges
#define FF 64         // F_IN = F_OUT
#define PP 8          // periods
#define NPAD 50048    // padded rows (multiple of 64, >= max GEMM tile row)

typedef _Float16 half8 __attribute__((ext_vector_type(8)));
typedef float floatx4 __attribute__((ext_vector_type(4)));

static constexpr size_t al512(size_t x) { return (x + 511) & ~size_t(511); }
static constexpr size_t OFF_DEG  = 0;                                  // float[NN]
static constexpr size_t OFF_CNT  = al512(OFF_DEG  + (size_t)NN*4);     // int[NN]
static constexpr size_t OFF_DIS  = al512(OFF_CNT  + (size_t)NN*4);     // float[NN]
static constexpr size_t OFF_ROWP = al512(OFF_DIS  + (size_t)NN*4);     // int[NN+1]
static constexpr size_t OFF_CUR  = al512(OFF_ROWP + (size_t)(NN+1)*4); // int[NN]
static constexpr size_t OFF_PART = al512(OFF_CUR  + (size_t)NN*4);     // int[64]
static constexpr size_t OFF_CSRP = al512(OFF_PART + 64*4);             // int2[EE]
static constexpr size_t OFF_BIAS = al512(OFF_CSRP + (size_t)EE*8);     // float[192]
static constexpr size_t OFF_WC2  = al512(OFF_BIAS + 192*4);            // float[64]
static constexpr size_t OFF_WFRG = al512(OFF_WC2  + 64*4);             // half[24576]
static constexpr size_t OFF_XB   = al512(OFF_WFRG + (size_t)24576*2);  // half[NPAD*512]
static constexpr size_t OFF_TB   = al512(OFF_XB   + (size_t)NPAD*512*2); // half[NPAD*512]

// ---- K1: out-degree by src (float) + in-degree count by dst (int) ----------
__global__ void k_deg_cnt(const int* __restrict__ src, const int* __restrict__ dst,
                          const float* __restrict__ ew,
                          float* __restrict__ deg, int* __restrict__ cnt) {
    int e = blockIdx.x * 256 + threadIdx.x;
    if (e < EE) {
        atomicAdd(deg + src[e], ew[e]);
        atomicAdd(cnt + dst[e], 1);
    }
}

// ---- K2: dis[n] = deg>0 ? rsqrt(max(deg,1e-12)) : 0 ------------------------
__global__ void k_dis(const float* __restrict__ deg, float* __restrict__ dis) {
    int n = blockIdx.x * 256 + threadIdx.x;
    if (n < NN) {
        float d = deg[n];
        dis[n] = d > 0.f ? rsqrtf(fmaxf(d, 1e-12f)) : 0.f;
    }
}

// ---- K3a: per-block (1024-wide) inclusive scan via wave shfl ---------------
__global__ void k_scanA(const int* __restrict__ cnt, int* __restrict__ incl,
                        int* __restrict__ partial) {
    int tid = threadIdx.x;
    int i = blockIdx.x * 1024 + tid;
    int v = (i < NN) ? cnt[i] : 0;
    int lane = tid & 63, w = tid >> 6;
    int s = v;
#pragma unroll
    for (int d = 1; d < 64; d <<= 1) {
        int t = __shfl_up(s, d);
        if (lane >= d) s += t;
    }
    __shared__ int wsum[16];
    if (lane == 63) wsum[w] = s;
    __syncthreads();
    if (w == 0) {
        int x = (lane < 16) ? wsum[lane] : 0;
#pragma unroll
        for (int d = 1; d < 16; d <<= 1) {
            int t = __shfl_up(x, d);
            if (lane >= d) x += t;
        }
        if (lane < 16) wsum[lane] = x;
    }
    __syncthreads();
    int inc = s + (w > 0 ? wsum[w - 1] : 0);
    if (i < NN) incl[i] = inc;
    if (tid == 1023) partial[blockIdx.x] = inc;  // block total (tail padded w/ 0)
}

// ---- K3b: scan the 49 block partials (in place -> exclusive), total --------
__global__ void k_scanB(int* __restrict__ partial, int* __restrict__ row_ptr, int nblk) {
    if (threadIdx.x == 0) {
        int run = 0;
        for (int b = 0; b < nblk; ++b) { int t = partial[b]; partial[b] = run; run += t; }
        row_ptr[NN] = run;
    }
}

// ---- K3c: add offsets -> exclusive row_ptr + cursor ------------------------
__global__ void k_scanC(const int* __restrict__ incl, const int* __restrict__ cnt,
                        const int* __restrict__ partial,
                        int* __restrict__ row_ptr, int* __restrict__ cursor) {
    int i = blockIdx.x * 1024 + threadIdx.x;
    if (i < NN) {
        int excl = partial[blockIdx.x] + incl[i] - cnt[i];
        row_ptr[i] = excl;
        cursor[i] = excl;
    }
}

// ---- K4: scatter edges into CSR buckets by dst (packed 8B) -----------------
__global__ void k_scatter(const int* __restrict__ src, const int* __restrict__ dst,
                          const float* __restrict__ ew, const float* __restrict__ dis,
                          int* __restrict__ cursor, int2* __restrict__ csr) {
    int e = blockIdx.x * 256 + threadIdx.x;
    if (e < EE) {
        int s = src[e], d = dst[e];
        float wn = -dis[s] * ew[e] * dis[d];
        int pos = atomicAdd(cursor + d, 1);
        int2 pr; pr.x = s; pr.y = __float_as_int(wn);
        csr[pos] = pr;
    }
}

// ---- K5: transpose+cvt X (N,64,8) f32 -> XBuf[n][p][f] f16 -----------------
__global__ void k_xpose(const float* __restrict__ X, _Float16* __restrict__ XB) {
    __shared__ _Float16 tile[4][512];
    int wid = threadIdx.x >> 6, lane = threadIdx.x & 63;
    int n = blockIdx.x * 4 + wid;
    if (n < NN) {
        const float4* xp = (const float4*)(X + (size_t)n * 512 + lane * 8);
        float4 a = xp[0], b = xp[1];
        float v[8] = {a.x, a.y, a.z, a.w, b.x, b.y, b.z, b.w};
#pragma unroll
        for (int p = 0; p < PP; ++p)               // [p][f] layout, f = lane
            tile[wid][p * 64 + lane] = (_Float16)v[p];
        half8 vv = *(const half8*)&tile[wid][lane * 8];
        *(half8*)(XB + (size_t)n * 512 + lane * 8) = vv;
    }
}

// ---- K6: SpMM gather: TB[n][p][f] = sum_e wn * XB[src][p][f] ---------------
__global__ void k_spmm(const _Float16* __restrict__ XB, const int* __restrict__ row_ptr,
                       const int2* __restrict__ csr, _Float16* __restrict__ TB) {
    int wid = threadIdx.x >> 6, lane = threadIdx.x & 63;
    int n = blockIdx.x * 4 + wid;
    if (n >= NN) return;
    float acc[8] = {0.f, 0.f, 0.f, 0.f, 0.f, 0.f, 0.f, 0.f};
    int beg = row_ptr[n], end = row_ptr[n + 1];
    int k = beg;
    for (; k + 3 < end; k += 4) {
        int2 e0 = csr[k], e1 = csr[k + 1], e2 = csr[k + 2], e3 = csr[k + 3];
        half8 a = *((const half8*)(XB + (size_t)e0.x * 512) + lane);
        half8 b = *((const half8*)(XB + (size_t)e1.x * 512) + lane);
        half8 c = *((const half8*)(XB + (size_t)e2.x * 512) + lane);
        half8 d = *((const half8*)(XB + (size_t)e3.x * 512) + lane);
        float w0 = __int_as_float(e0.y), w1 = __int_as_float(e1.y);
        float w2 = __int_as_float(e2.y), w3 = __int_as_float(e3.y);
#pragma unroll
        for (int j = 0; j < 8; ++j) {
            acc[j] += w0 * (float)a[j];
            acc[j] += w1 * (float)b[j];
            acc[j] += w2 * (float)c[j];
            acc[j] += w3 * (float)d[j];
        }
    }
    for (; k < end; ++k) {
        int2 e0 = csr[k];
        half8 a = *((const half8*)(XB + (size_t)e0.x * 512) + lane);
        float w0 = __int_as_float(e0.y);
#pragma unroll
        for (int j = 0; j < 8; ++j) acc[j] += w0 * (float)a[j];
    }
    half8 st;
#pragma unroll
    for (int j = 0; j < 8; ++j) st[j] = (_Float16)acc[j];
    *(half8*)(TB + (size_t)n * 512 + lane * 8) = st;
}

// ---- K7: weight prep: pack W into MFMA B-fragment layout + biases ----------
__global__ void k_prep(const float* __restrict__ Wx0, const float* __restrict__ Wx1,
                       const float* __restrict__ bx, const float* __restrict__ bh,
                       const float* __restrict__ wc, const float* __restrict__ bg,
                       _Float16* __restrict__ Wfrag, float* __restrict__ biasv,
                       float* __restrict__ wc2) {
    int t = blockIdx.x * 256 + threadIdx.x;
    const int gmap[3] = {0, 2, 3};
    if (t < 24576) {
        int j8 = t & 7;
        int lane = (t >> 3) & 63;
        int rem = t >> 9;           // [0,48)
        int ct = rem % 12;
        int ks = rem / 12;
        int k = ks * 32 + (lane >> 4) * 8 + j8;
        int gp = ct >> 2;
        int g = gmap[gp];
        int j64 = (ct & 3) * 16 + (lane & 15);
        float val = (k < 64) ? Wx0[((size_t)g * 64 + k) * 64 + j64]
                             : Wx1[((size_t)g * 64 + (k - 64)) * 64 + j64];
        Wfrag[t] = (_Float16)val;
    }
    if (t < 192) {
        int gp = t / 64, j = t % 64;
        int g = gmap[gp];
        biasv[t] = bx[g * 64 + j] + bh[g * 64 + j] + bg[g * 64 + j];
    }
    if (t < 64) wc2[t] = wc[2 * 64 + t];
}

__device__ __forceinline__ float fast_rcp(float x) { return __builtin_amdgcn_rcpf(x); }
__device__ __forceinline__ float sigmoidf_fast(float x) {
    return fast_rcp(1.f + __expf(-x));          // v_exp + v_rcp, no slow division
}
__device__ __forceinline__ float tanhf_fast(float x) {
    return 1.f - 2.f * fast_rcp(1.f + __expf(2.f * x));
}

// ---- K8: MFMA GEMM (N x 128) @ (128 x 192) per period + fused LSTM epilogue
// One wave per block; wave handles 64 rows (4 row-frags) x 192 cols.
// B fragments staged once in LDS (48 KB); A loads software-prefetched.
__global__ __launch_bounds__(64, 1) void k_gemm(const _Float16* __restrict__ XB,
                                                const _Float16* __restrict__ TB,
                                                const _Float16* __restrict__ Wfrag,
                                                const float* __restrict__ biasv,
                                                const float* __restrict__ wc2,
                                                float* __restrict__ out) {
    __shared__ _Float16 Wl[24576];  // 48 KB: full B in MFMA fragment layout
    const int lane = threadIdx.x;
    const half8* __restrict__ Wg = (const half8*)Wfrag;
    half8* Wl8 = (half8*)Wl;
#pragma unroll
    for (int i = 0; i < 48; ++i) Wl8[i * 64 + lane] = Wg[i * 64 + lane];
    __syncthreads();

    const int n0 = blockIdx.x * 64;
    const int jj = lane & 15, quad = lane >> 4;

    float bi[4], bc[4], bo[4], wcv[4];
#pragma unroll
    for (int c4 = 0; c4 < 4; ++c4) {
        int j = c4 * 16 + jj;
        bi[c4] = biasv[j];
        bc[c4] = biasv[64 + j];
        bo[c4] = biasv[128 + j];
        wcv[c4] = wc2[j];
    }

    const half8* __restrict__ Ax[4];
    const half8* __restrict__ At[4];
#pragma unroll
    for (int r = 0; r < 4; ++r) {
        int row = n0 + r * 16 + jj;            // < NPAD always
        Ax[r] = (const half8*)(XB + (size_t)row * 512) + quad;
        At[r] = (const half8*)(TB + (size_t)row * 512) + quad;
    }

    floatx4 outacc[4][4];
#pragma unroll
    for (int r = 0; r < 4; ++r)
#pragma unroll
        for (int c4 = 0; c4 < 4; ++c4) outacc[r][c4] = (floatx4){0.f, 0.f, 0.f, 0.f};

    half8 af[4][4];                            // [rowfrag][ks]
#pragma unroll
    for (int r = 0; r < 4; ++r) {
        af[r][0] = Ax[r][0]; af[r][1] = Ax[r][4];
        af[r][2] = At[r][0]; af[r][3] = At[r][4];
    }

#pragma unroll
    for (int p = 0; p < PP; ++p) {
        half8 afn[4][4];
        if (p + 1 < PP) {                      // prefetch next period's A
            int o = (p + 1) * 8;
#pragma unroll
            for (int r = 0; r < 4; ++r) {
                afn[r][0] = Ax[r][o];     afn[r][1] = Ax[r][o + 4];
                afn[r][2] = At[r][o];     afn[r][3] = At[r][o + 4];
            }
        }
#pragma unroll
        for (int c4 = 0; c4 < 4; ++c4) {
            floatx4 ai[4], ac[4], ao[4];
#pragma unroll
            for (int r = 0; r < 4; ++r) {
                ai[r] = (floatx4){0.f, 0.f, 0.f, 0.f};
                ac[r] = (floatx4){0.f, 0.f, 0.f, 0.f};
                ao[r] = (floatx4){0.f, 0.f, 0.f, 0.f};
            }
#pragma unroll
            for (int ks = 0; ks < 4; ++ks) {
                half8 bfi = Wl8[(ks * 12 + c4) * 64 + lane];
                half8 bfc = Wl8[(ks * 12 + 4 + c4) * 64 + lane];
                half8 bfo = Wl8[(ks * 12 + 8 + c4) * 64 + lane];
#pragma unroll
                for (int r = 0; r < 4; ++r) {
                    ai[r] = __builtin_amdgcn_mfma_f32_16x16x32_f16(af[r][ks], bfi, ai[r], 0, 0, 0);
                    ac[r] = __builtin_amdgcn_mfma_f32_16x16x32_f16(af[r][ks], bfc, ac[r], 0, 0, 0);
                    ao[r] = __builtin_amdgcn_mfma_f32_16x16x32_f16(af[r][ks], bfo, ao[r], 0, 0, 0);
                }
            }
            // fused epilogue: I=sig(ai); T=tanh(ac); Cn=I*T; O=sig(ao+wc2*Cn)
#pragma unroll
            for (int r = 0; r < 4; ++r)
#pragma unroll
                for (int rr = 0; rr < 4; ++rr) {
                    float aiv = ai[r][rr] + bi[c4];
                    float acv = ac[r][rr] + bc[c4];
                    float aov = ao[r][rr] + bo[c4];
                    float I = sigmoidf_fast(aiv);
                    float T = tanhf_fast(acv);
                    float Cn = I * T;
                    float O = sigmoidf_fast(aov + wcv[c4] * Cn);
                    outacc[r][c4][rr] += O * tanhf_fast(Cn);
                }
        }
        if (p + 1 < PP) {
#pragma unroll
            for (int r = 0; r < 4; ++r)
#pragma unroll
                for (int ks = 0; ks < 4; ++ks) af[r][ks] = afn[r][ks];
        }
    }
    // store: row n = n0 + r*16 + quad*4 + rr, col = c4*16 + jj
#pragma unroll
    for (int r = 0; r < 4; ++r)
#pragma unroll
        for (int c4 = 0; c4 < 4; ++c4)
#pragma unroll
            for (int rr = 0; rr < 4; ++rr) {
                int n = n0 + r * 16 + quad * 4 + rr;
                if (n < NN) out[(size_t)n * 64 + c4 * 16 + jj] = outacc[r][c4][rr];
            }
}

extern "C" void kernel_launch(void* const* d_in, const int* in_sizes, int n_in,
                              void* d_out, int out_size, void* d_ws, size_t ws_size,
                              hipStream_t stream) {
    const float* X   = (const float*)d_in[0];
    const int*   ei  = (const int*)d_in[1];
    const float* ew  = (const float*)d_in[2];
    const float* Wx0 = (const float*)d_in[3];
    const float* Wx1 = (const float*)d_in[4];
    const float* bx  = (const float*)d_in[5];
    // d_in[6], d_in[7] (Wh0, Wh1) are dead: H=0
    const float* bh  = (const float*)d_in[8];
    const float* wc  = (const float*)d_in[9];
    const float* bg  = (const float*)d_in[10];
    float* out = (float*)d_out;

    const int* src = ei;
    const int* dst = ei + EE;

    char* ws = (char*)d_ws;
    float* deg     = (float*)(ws + OFF_DEG);
    int*   cnt     = (int*)(ws + OFF_CNT);
    float* dis     = (float*)(ws + OFF_DIS);
    int*   row_ptr = (int*)(ws + OFF_ROWP);
    int*   cursor  = (int*)(ws + OFF_CUR);
    int*   partial = (int*)(ws + OFF_PART);
    int2*  csr     = (int2*)(ws + OFF_CSRP);
    float* biasv   = (float*)(ws + OFF_BIAS);
    float* wc2     = (float*)(ws + OFF_WC2);
    _Float16* Wfrag = (_Float16*)(ws + OFF_WFRG);
    _Float16* XB    = (_Float16*)(ws + OFF_XB);
    _Float16* TB    = (_Float16*)(ws + OFF_TB);

    // zero deg + cnt (contiguous region at front of ws)
    hipMemsetAsync(ws, 0, OFF_CNT + (size_t)NN * 4, stream);

    const int NSCAN = (NN + 1023) / 1024;  // 49
    k_deg_cnt<<<(EE + 255) / 256, 256, 0, stream>>>(src, dst, ew, deg, cnt);
    k_dis<<<(NN + 255) / 256, 256, 0, stream>>>(deg, dis);
    k_scanA<<<NSCAN, 1024, 0, stream>>>(cnt, cursor, partial);  // cursor <- inclusive scan
    k_scanB<<<1, 64, 0, stream>>>(partial, row_ptr, NSCAN);
    k_scanC<<<NSCAN, 1024, 0, stream>>>(cursor, cnt, partial, row_ptr, cursor);
    k_scatter<<<(EE + 255) / 256, 256, 0, stream>>>(src, dst, ew, dis, cursor, csr);
    k_xpose<<<(NN + 3) / 4, 256, 0, stream>>>(X, XB);
    k_spmm<<<(NN + 3) / 4, 256, 0, stream>>>(XB, row_ptr, csr, TB);
    k_prep<<<96, 256, 0, stream>>>(Wx0, Wx1, bx, bh, wc, bg, Wfrag, biasv, wc2);
    k_gemm<<<(NN + 63) / 64, 64, 0, stream>>>(XB, TB, Wfrag, biasv, wc2, out);
}